// Round 3
// baseline (2329.582 us; speedup 1.0000x reference)
//
#include <hip/hip_runtime.h>
#include <cstdint>
#include <cstddef>

#define WS_ 8
#define DIM_ 192
#define HEADS_ 6
#define HD_ 32
#define HH_ 56
#define NW_ 7
#define NWIN_ 49
#define LTOK_ 3136
#define NTOK_ 200704
#define NWTOT_ 3136
#define SHIFT_ 4
#define SCALE_ 0.17677669529663687f

typedef unsigned short ushort_t;
typedef __attribute__((ext_vector_type(8))) short short8;
typedef __attribute__((ext_vector_type(4))) float floatx4;
typedef __attribute__((ext_vector_type(8))) unsigned short ushort8;

__device__ __forceinline__ float b2f(ushort_t u) {
    union { unsigned int i; float f; } c; c.i = ((unsigned int)u) << 16; return c.f;
}
__device__ __forceinline__ ushort_t f2b(float f) {
    union { float f; unsigned int i; } c; c.f = f;
    unsigned int u = c.i;
    unsigned int r = (u + 0x7FFFu + ((u >> 16) & 1u)) >> 16;
    return (ushort_t)r;
}

// global window-token row r (win*64 + n) -> image token index, incl. roll.
// Same map serves gather (LN1) and scatter (proj): self-inverse usage.
__device__ __forceinline__ int win_row_to_img(int r) {
    int win = r >> 6, n = r & 63;
    int b = win / NWIN_, wI = win - b * NWIN_;
    int wh = wI / NW_, wwi = wI - wh * NW_;
    int i = n >> 3, j = n & 7;
    int hh = wh * WS_ + i + SHIFT_; if (hh >= HH_) hh -= HH_;
    int ww = wwi * WS_ + j + SHIFT_; if (ww >= HH_) ww -= HH_;
    return b * LTOK_ + hh * HH_ + ww;
}

// f32 weight [K][N] -> bf16 transposed [N][K]
__global__ void transpose_kernel(const float* __restrict__ in,
                                 ushort_t* __restrict__ out, int K, int N) {
    int id = blockIdx.x * 256 + threadIdx.x;
    if (id >= K * N) return;
    int k = id / N, n = id - k * N;
    out[(size_t)n * K + k] = f2b(in[id]);
}

// One wave per token; lane covers cols {l, l+64, l+128}. f32 in, bf16 out.
template <bool PERMUTE>
__global__ __launch_bounds__(256) void ln_kernel(const float* __restrict__ xin,
                                                 const float* __restrict__ w,
                                                 const float* __restrict__ bia,
                                                 ushort_t* __restrict__ out,
                                                 int rowOff) {
    int t = blockIdx.x * 4 + (threadIdx.x >> 6);
    int lane = threadIdx.x & 63;
    int src = PERMUTE ? win_row_to_img(rowOff + t) : t;
    const float* xp = xin + (size_t)src * DIM_;
    float v0 = xp[lane];
    float v1 = xp[lane + 64];
    float v2 = xp[lane + 128];
    float s = v0 + v1 + v2;
    float ss = v0 * v0 + v1 * v1 + v2 * v2;
#pragma unroll
    for (int o = 32; o > 0; o >>= 1) {
        s += __shfl_xor(s, o);
        ss += __shfl_xor(ss, o);
    }
    float mu = s * (1.0f / 192.0f);
    float var = ss * (1.0f / 192.0f) - mu * mu;
    float inv = rsqrtf(var + 1e-5f);
    ushort_t* op = out + (size_t)t * DIM_;
    op[lane]       = f2b((v0 - mu) * inv * w[lane]       + bia[lane]);
    op[lane + 64]  = f2b((v1 - mu) * inv * w[lane + 64]  + bia[lane + 64]);
    op[lane + 128] = f2b((v2 - mu) * inv * w[lane + 128] + bia[lane + 128]);
}

#define EPI_STORE 0
#define EPI_GELU 1
#define EPI_PROJ 2
#define EPI_FC2 3

// C[M,N] = A[M,K] @ W[K,N] + bias; A,Bt bf16; bias f32.
// STORE/GELU write bf16; PROJ/FC2 write f32 (+f32 residual aux).
template <int EPI>
__global__ __launch_bounds__(256) void gemm_kernel(const ushort_t* __restrict__ A,
                                                   const ushort_t* __restrict__ Bt,
                                                   const float* __restrict__ bias,
                                                   void* __restrict__ outv,
                                                   const float* __restrict__ aux,
                                                   int K, int N, int rowOff) {
    int wave = threadIdx.x >> 6, lane = threadIdx.x & 63;
    int quad = lane >> 4, l16 = lane & 15;
    int row0 = blockIdx.x * 64 + wave * 16;
    int n0 = blockIdx.y * 64;
    const ushort_t* aBase = A + (size_t)(row0 + l16) * K + quad * 8;
    const ushort_t* bBase = Bt + (size_t)(n0 + l16) * K + quad * 8;
    size_t bRowStride = (size_t)16 * K;

    floatx4 acc[4];
#pragma unroll
    for (int t = 0; t < 4; ++t)
#pragma unroll
        for (int e = 0; e < 4; ++e) acc[t][e] = 0.0f;

    int nk = K >> 5;
    for (int kk = 0; kk < nk; ++kk) {
        short8 a = *(const short8*)(aBase + kk * 32);
#pragma unroll
        for (int t = 0; t < 4; ++t) {
            short8 b = *(const short8*)(bBase + (size_t)t * bRowStride + kk * 32);
            acc[t] = __builtin_amdgcn_mfma_f32_16x16x32_bf16(a, b, acc[t], 0, 0, 0);
        }
    }

#pragma unroll
    for (int t = 0; t < 4; ++t) {
        int c = n0 + t * 16 + l16;
        float bs = bias[c];
#pragma unroll
        for (int r = 0; r < 4; ++r) {
            int rr = row0 + quad * 4 + r;
            float val = acc[t][r] + bs;
            if (EPI == EPI_STORE) {
                ((ushort_t*)outv)[(size_t)rr * N + c] = f2b(val);
            } else if (EPI == EPI_GELU) {
                float g = 0.5f * val * (1.0f + erff(val * 0.70710678118654752f));
                ((ushort_t*)outv)[(size_t)rr * N + c] = f2b(g);
            } else if (EPI == EPI_PROJ) {
                int dst = win_row_to_img(rowOff + rr);
                size_t idx = (size_t)dst * DIM_ + c;
                ((float*)outv)[idx] = val + aux[idx];   // + shortcut x -> x1
            } else {  // EPI_FC2
                size_t idx = (size_t)rr * DIM_ + c;
                ((float*)outv)[idx] = val + aux[idx];   // + x1 -> final out
            }
        }
    }
}

// One block per (local window, head). qkv rows chunk-local bf16: [winl*64+n][576].
__global__ __launch_bounds__(256) void attn_kernel(const ushort_t* __restrict__ qkv,
                                                   const float* __restrict__ rpb,
                                                   ushort_t* __restrict__ aout,
                                                   int win0) {
    __shared__ float qs[64][36], ks[64][36], vs[64][36];
    __shared__ float S[64][65];
    __shared__ int regid[64];
    int bid = blockIdx.x;
    int winl = bid / HEADS_, head = bid - winl * HEADS_;
    int wI = (win0 + winl) % NWIN_;
    int wh = wI / NW_, wwi = wI - wh * NW_;
    int tid = threadIdx.x;
    int row = tid >> 2, c0 = (tid & 3) * 8;
    size_t base = (size_t)(winl * 64 + row) * (3 * DIM_) + head * HD_ + c0;
    ushort8 qv = *(const ushort8*)(qkv + base);
    ushort8 kv = *(const ushort8*)(qkv + base + DIM_);
    ushort8 vv = *(const ushort8*)(qkv + base + 2 * DIM_);
#pragma unroll
    for (int e = 0; e < 8; ++e) {
        qs[row][c0 + e] = b2f(qv[e]) * SCALE_;
        ks[row][c0 + e] = b2f(kv[e]);
        vs[row][c0 + e] = b2f(vv[e]);
    }
    if (tid < 64) {
        int i = tid >> 3, j = tid & 7;
        int hh = wh * WS_ + i, ww = wwi * WS_ + j;
        int rh = (hh < HH_ - WS_) ? 0 : ((hh < HH_ - SHIFT_) ? 1 : 2);
        int rw = (ww < HH_ - WS_) ? 0 : ((ww < HH_ - SHIFT_) ? 1 : 2);
        regid[tid] = rh * 3 + rw;
    }
    __syncthreads();

    int n = tid >> 2, qq = tid & 3;
    float qr[32];
#pragma unroll
    for (int e = 0; e < 8; ++e) {
        floatx4 t4 = *(const floatx4*)&qs[n][e * 4];
        qr[e * 4 + 0] = t4[0]; qr[e * 4 + 1] = t4[1];
        qr[e * 4 + 2] = t4[2]; qr[e * 4 + 3] = t4[3];
    }
    int i1 = n >> 3, j1 = n & 7;
    int rg1 = regid[n];
#pragma unroll 4
    for (int mi = 0; mi < 16; ++mi) {
        int m = mi * 4 + qq;
        float d = 0.0f;
#pragma unroll
        for (int e = 0; e < 8; ++e) {
            floatx4 k4 = *(const floatx4*)&ks[m][e * 4];
            d += qr[e * 4 + 0] * k4[0] + qr[e * 4 + 1] * k4[1] +
                 qr[e * 4 + 2] * k4[2] + qr[e * 4 + 3] * k4[3];
        }
        int i2 = m >> 3, j2 = m & 7;
        int rel = (i1 - i2 + 7) * 15 + (j1 - j2 + 7);
        d += rpb[rel * HEADS_ + head];
        if (regid[m] != rg1) d -= 100.0f;
        S[n][m] = d;
    }
    __syncthreads();

    if (tid < 64) {
        float mx = -1e30f;
        for (int m = 0; m < 64; ++m) mx = fmaxf(mx, S[tid][m]);
        float sum = 0.0f;
        for (int m = 0; m < 64; ++m) {
            float e = __expf(S[tid][m] - mx);
            S[tid][m] = e;
            sum += e;
        }
        float rs = 1.0f / sum;
        for (int m = 0; m < 64; ++m) S[tid][m] *= rs;
    }
    __syncthreads();

    int d0 = (tid & 3) * 8;
    float o[8];
#pragma unroll
    for (int e = 0; e < 8; ++e) o[e] = 0.0f;
    for (int m = 0; m < 64; ++m) {
        float p = S[n][m];
        floatx4 va = *(const floatx4*)&vs[m][d0];
        floatx4 vb = *(const floatx4*)&vs[m][d0 + 4];
        o[0] += p * va[0]; o[1] += p * va[1]; o[2] += p * va[2]; o[3] += p * va[3];
        o[4] += p * vb[0]; o[5] += p * vb[1]; o[6] += p * vb[2]; o[7] += p * vb[3];
    }
    ushort8 pk;
#pragma unroll
    for (int e = 0; e < 8; ++e) pk[e] = f2b(o[e]);
    *(ushort8*)(aout + (size_t)(winl * 64 + n) * DIM_ + head * HD_ + d0) = pk;
}

extern "C" void kernel_launch(void* const* d_in, const int* in_sizes, int n_in,
                              void* d_out, int out_size, void* d_ws, size_t ws_size,
                              hipStream_t stream) {
    const float* x      = (const float*)d_in[0];
    const float* ln1_w  = (const float*)d_in[1];
    const float* ln1_b  = (const float*)d_in[2];
    const float* qkv_w  = (const float*)d_in[3];
    const float* qkv_b  = (const float*)d_in[4];
    const float* proj_w = (const float*)d_in[5];
    const float* proj_b = (const float*)d_in[6];
    const float* rpb    = (const float*)d_in[7];
    const float* ln2_w  = (const float*)d_in[8];
    const float* ln2_b  = (const float*)d_in[9];
    const float* fc1_w  = (const float*)d_in[10];
    const float* fc1_b  = (const float*)d_in[11];
    const float* fc2_w  = (const float*)d_in[12];
    const float* fc2_b  = (const float*)d_in[13];

    char* ws = (char*)d_ws;
    size_t off = 0;
    auto alloc = [&](size_t bytes) -> void* {
        void* p = ws + off;
        off += (bytes + 255) & ~(size_t)255;
        return p;
    };
    ushort_t* qkv_wt  = (ushort_t*)alloc((size_t)576 * 192 * 2);
    ushort_t* proj_wt = (ushort_t*)alloc((size_t)192 * 192 * 2);
    ushort_t* fc1_wt  = (ushort_t*)alloc((size_t)768 * 192 * 2);
    ushort_t* fc2_wt  = (ushort_t*)alloc((size_t)192 * 768 * 2);

    // x1 lives in d_out (f32; fully written by proj scatter before any read).
    float* x1 = (float*)d_out;

    // Chunk sizing vs actual ws_size. Per-row scratch (bf16):
    // phase A: 192 (xw) + 576 (qkv) = 1536 B; phase B: 192 + 768 = 1920 B.
    size_t budget = (ws_size > off + 4096) ? (ws_size - off - 4096) : 0;
    long rows = (long)(budget / 1920);
    rows = (rows / 64) * 64;
    if (rows < 64) rows = 64;
    if (rows > NTOK_) rows = NTOK_;
    int chunkRows = (int)rows;
    int Wc = chunkRows / 64;
    if (Wc > NWTOT_) Wc = NWTOT_;

    ushort_t* bufS = (ushort_t*)alloc((size_t)chunkRows * 192 * 2);  // xw / attn_out / xn2
    ushort_t* bufL = (ushort_t*)alloc((size_t)chunkRows * 768 * 2);  // qkv / h
    (void)n_in; (void)in_sizes; (void)out_size;

    transpose_kernel<<<(192 * 576 + 255) / 256, 256, 0, stream>>>(qkv_w, qkv_wt, 192, 576);
    transpose_kernel<<<(192 * 192 + 255) / 256, 256, 0, stream>>>(proj_w, proj_wt, 192, 192);
    transpose_kernel<<<(192 * 768 + 255) / 256, 256, 0, stream>>>(fc1_w, fc1_wt, 192, 768);
    transpose_kernel<<<(768 * 192 + 255) / 256, 256, 0, stream>>>(fc2_w, fc2_wt, 768, 192);

    // ---- Phase A: LN1+roll+partition -> qkv -> attention -> proj(+x) -> x1
    for (int w0 = 0; w0 < NWTOT_; w0 += Wc) {
        int wc = NWTOT_ - w0 < Wc ? NWTOT_ - w0 : Wc;
        int rowsA = wc * 64;
        ln_kernel<true><<<rowsA / 4, 256, 0, stream>>>(x, ln1_w, ln1_b, bufS, w0 * 64);
        dim3 gq(rowsA / 64, 576 / 64);
        gemm_kernel<EPI_STORE><<<gq, 256, 0, stream>>>(bufS, qkv_wt, qkv_b, bufL, nullptr, 192, 576, 0);
        attn_kernel<<<wc * HEADS_, 256, 0, stream>>>(bufL, rpb, bufS, w0);
        dim3 gp(rowsA / 64, 192 / 64);
        gemm_kernel<EPI_PROJ><<<gp, 256, 0, stream>>>(bufS, proj_wt, proj_b, x1, x, 192, 192, w0 * 64);
    }

    // ---- Phase B: LN2 -> fc1+gelu -> fc2(+x1) -> d_out
    for (int t0 = 0; t0 < NTOK_; t0 += chunkRows) {
        int tc = NTOK_ - t0 < chunkRows ? NTOK_ - t0 : chunkRows;
        ln_kernel<false><<<tc / 4, 256, 0, stream>>>(x1 + (size_t)t0 * 192, ln2_w, ln2_b, bufS, 0);
        dim3 g1(tc / 64, 768 / 64);
        gemm_kernel<EPI_GELU><<<g1, 256, 0, stream>>>(bufS, fc1_wt, fc1_b, bufL, nullptr, 192, 768, 0);
        dim3 g2(tc / 64, 192 / 64);
        gemm_kernel<EPI_FC2><<<g2, 256, 0, stream>>>(bufL, fc2_wt, fc2_b,
                                                     x1 + (size_t)t0 * 192,
                                                     x1 + (size_t)t0 * 192, 768, 192, 0);
    }
}

// Round 5
// 1251.448 us; speedup vs baseline: 1.8615x; 1.8615x over previous
//
#include <hip/hip_runtime.h>
#include <cstdint>
#include <cstddef>

#define WS_ 8
#define DIM_ 192
#define HEADS_ 6
#define HD_ 32
#define HH_ 56
#define NW_ 7
#define NWIN_ 49
#define LTOK_ 3136
#define NTOK_ 200704
#define NWTOT_ 3136
#define SHIFT_ 4
#define SCALE_ 0.17677669529663687f

typedef unsigned short ushort_t;
typedef __attribute__((ext_vector_type(8))) short short8;
typedef __attribute__((ext_vector_type(4))) float floatx4;
typedef __attribute__((ext_vector_type(8))) unsigned short ushort8;

__device__ __forceinline__ float b2f(ushort_t u) {
    union { unsigned int i; float f; } c; c.i = ((unsigned int)u) << 16; return c.f;
}
__device__ __forceinline__ ushort_t f2b(float f) {
    union { float f; unsigned int i; } c; c.f = f;
    unsigned int u = c.i;
    unsigned int r = (u + 0x7FFFu + ((u >> 16) & 1u)) >> 16;
    return (ushort_t)r;
}

__device__ __forceinline__ void load_lds16(const void* g, void* l) {
    __builtin_amdgcn_global_load_lds(
        (const __attribute__((address_space(1))) unsigned int*)g,
        (__attribute__((address_space(3))) unsigned int*)l, 16, 0, 0);
}

// global window-token row r (win*64 + n) -> image token index, incl. roll.
__device__ __forceinline__ int win_row_to_img(int r) {
    int win = r >> 6, n = r & 63;
    int b = win / NWIN_, wI = win - b * NWIN_;
    int wh = wI / NW_, wwi = wI - wh * NW_;
    int i = n >> 3, j = n & 7;
    int hh = wh * WS_ + i + SHIFT_; if (hh >= HH_) hh -= HH_;
    int ww = wwi * WS_ + j + SHIFT_; if (ww >= HH_) ww -= HH_;
    return b * LTOK_ + hh * HH_ + ww;
}

// f32 weight [K][N] -> bf16 transposed [N][K]
__global__ void transpose_kernel(const float* __restrict__ in,
                                 ushort_t* __restrict__ out, int K, int N) {
    int id = blockIdx.x * 256 + threadIdx.x;
    if (id >= K * N) return;
    int k = id / N, n = id - k * N;
    out[(size_t)n * K + k] = f2b(in[id]);
}

// One wave per token; lane covers cols {l, l+64, l+128}. f32 in, bf16 out.
template <bool PERMUTE>
__global__ __launch_bounds__(256) void ln_kernel(const float* __restrict__ xin,
                                                 const float* __restrict__ w,
                                                 const float* __restrict__ bia,
                                                 ushort_t* __restrict__ out,
                                                 int rowOff) {
    int t = blockIdx.x * 4 + (threadIdx.x >> 6);
    int lane = threadIdx.x & 63;
    int src = PERMUTE ? win_row_to_img(rowOff + t) : t;
    const float* xp = xin + (size_t)src * DIM_;
    float v0 = xp[lane];
    float v1 = xp[lane + 64];
    float v2 = xp[lane + 128];
    float s = v0 + v1 + v2;
    float ss = v0 * v0 + v1 * v1 + v2 * v2;
#pragma unroll
    for (int o = 32; o > 0; o >>= 1) {
        s += __shfl_xor(s, o);
        ss += __shfl_xor(ss, o);
    }
    float mu = s * (1.0f / 192.0f);
    float var = ss * (1.0f / 192.0f) - mu * mu;
    float inv = rsqrtf(var + 1e-5f);
    ushort_t* op = out + (size_t)t * DIM_;
    op[lane]       = f2b((v0 - mu) * inv * w[lane]       + bia[lane]);
    op[lane + 64]  = f2b((v1 - mu) * inv * w[lane + 64]  + bia[lane + 64]);
    op[lane + 128] = f2b((v2 - mu) * inv * w[lane + 128] + bia[lane + 128]);
}

#define EPI_STORE 0
#define EPI_GELU 1
#define EPI_PROJ 2
#define EPI_FC2 3

// LDS-staged GEMM: C[M,N] = A[M,K] @ W[K,N] + bias; A,Bt bf16; bias f32.
// Block tile 128 rows x 192 cols, BK=32, double-buffered via global_load_lds.
// 4 waves in 2x2 grid, each computes 64x96 (4 row- x 6 col-tiles 16x16x32).
// LDS layout: A at [buf*8192 + row*64 + kByte], B at 16384 + [buf*12288 + ...].
template <int EPI>
__global__ __launch_bounds__(256) void gemm_kernel(const ushort_t* __restrict__ A,
                                                   const ushort_t* __restrict__ Bt,
                                                   const float* __restrict__ bias,
                                                   void* __restrict__ outv,
                                                   const float* __restrict__ aux,
                                                   int K, int N, int rowOff) {
    __shared__ char smem[40960];  // A: 2 x 8192, B: 2 x 12288

    int tid = threadIdx.x;
    int wave = tid >> 6, lane = tid & 63;
    int quad = lane >> 4, l16 = lane & 15;
    int wave_r = wave >> 1, wave_c = wave & 1;   // 2x2 wave grid
    int row0 = blockIdx.x * 128;
    int n0 = blockIdx.y * 192;

    floatx4 acc[4][6];
#pragma unroll
    for (int rt = 0; rt < 4; ++rt)
#pragma unroll
        for (int ct = 0; ct < 6; ++ct)
#pragma unroll
            for (int e = 0; e < 4; ++e) acc[rt][ct][e] = 0.0f;

    int nk = K >> 5;

    // stage A slice (128x32 bf16 = 8192 B) + B slice (192x32 bf16 = 12288 B)
    auto stage = [&](int kk, int buf) {
#pragma unroll
        for (int j = 0; j < 2; ++j) {
            int o = (tid + j * 256) * 16;          // byte offset within A slice
            int row = o >> 6, kb = o & 63;         // 64 B per row
            const ushort_t* g = A + (size_t)(row0 + row) * K + kk * 32 + (kb >> 1);
            load_lds16(g, smem + buf * 8192 + o);
        }
#pragma unroll
        for (int j = 0; j < 3; ++j) {
            int o = (tid + j * 256) * 16;          // byte offset within B slice
            int row = o >> 6, kb = o & 63;
            const ushort_t* g = Bt + (size_t)(n0 + row) * K + kk * 32 + (kb >> 1);
            load_lds16(g, smem + 16384 + buf * 12288 + o);
        }
    };

    stage(0, 0);
    for (int kk = 0; kk < nk; ++kk) {
        int cur = kk & 1;
        __syncthreads();                 // drains vmcnt: stage(kk) complete
        if (kk + 1 < nk) stage(kk + 1, cur ^ 1);

        short8 a[4];
#pragma unroll
        for (int rt = 0; rt < 4; ++rt)
            a[rt] = *(const short8*)(smem + cur * 8192 +
                     ((wave_r * 64 + rt * 16 + l16) * 64 + quad * 16));
#pragma unroll
        for (int ct = 0; ct < 6; ++ct) {
            short8 b = *(const short8*)(smem + 16384 + cur * 12288 +
                        ((wave_c * 96 + ct * 16 + l16) * 64 + quad * 16));
#pragma unroll
            for (int rt = 0; rt < 4; ++rt)
                acc[rt][ct] = __builtin_amdgcn_mfma_f32_16x16x32_bf16(a[rt], b, acc[rt][ct], 0, 0, 0);
        }
    }

#pragma unroll
    for (int ct = 0; ct < 6; ++ct) {
        int c = n0 + wave_c * 96 + ct * 16 + l16;
        float bs = bias[c];
#pragma unroll
        for (int rt = 0; rt < 4; ++rt) {
#pragma unroll
            for (int r = 0; r < 4; ++r) {
                int rr = row0 + wave_r * 64 + rt * 16 + quad * 4 + r;
                float val = acc[rt][ct][r] + bs;
                if (EPI == EPI_STORE) {
                    ((ushort_t*)outv)[(size_t)rr * N + c] = f2b(val);
                } else if (EPI == EPI_GELU) {
                    float g = 0.5f * val * (1.0f + erff(val * 0.70710678118654752f));
                    ((ushort_t*)outv)[(size_t)rr * N + c] = f2b(g);
                } else if (EPI == EPI_PROJ) {
                    int dst = win_row_to_img(rowOff + rr);
                    size_t idx = (size_t)dst * DIM_ + c;
                    ((float*)outv)[idx] = val + aux[idx];   // + shortcut x -> x1
                } else {  // EPI_FC2
                    size_t idx = (size_t)rr * DIM_ + c;
                    ((float*)outv)[idx] = val + aux[idx];   // + x1 -> final out
                }
            }
        }
    }
}

// One block per (local window, head). qkv rows chunk-local bf16: [winl*64+n][576].
__global__ __launch_bounds__(256) void attn_kernel(const ushort_t* __restrict__ qkv,
                                                   const float* __restrict__ rpb,
                                                   ushort_t* __restrict__ aout,
                                                   int win0) {
    __shared__ float qs[64][36], ks[64][36], vs[64][36];
    __shared__ float S[64][65];
    __shared__ int regid[64];
    int bid = blockIdx.x;
    int winl = bid / HEADS_, head = bid - winl * HEADS_;
    int wI = (win0 + winl) % NWIN_;
    int wh = wI / NW_, wwi = wI - wh * NW_;
    int tid = threadIdx.x;
    int row = tid >> 2, c0 = (tid & 3) * 8;
    size_t base = (size_t)(winl * 64 + row) * (3 * DIM_) + head * HD_ + c0;
    ushort8 qv = *(const ushort8*)(qkv + base);
    ushort8 kv = *(const ushort8*)(qkv + base + DIM_);
    ushort8 vv = *(const ushort8*)(qkv + base + 2 * DIM_);
#pragma unroll
    for (int e = 0; e < 8; ++e) {
        qs[row][c0 + e] = b2f(qv[e]) * SCALE_;
        ks[row][c0 + e] = b2f(kv[e]);
        vs[row][c0 + e] = b2f(vv[e]);
    }
    if (tid < 64) {
        int i = tid >> 3, j = tid & 7;
        int hh = wh * WS_ + i, ww = wwi * WS_ + j;
        int rh = (hh < HH_ - WS_) ? 0 : ((hh < HH_ - SHIFT_) ? 1 : 2);
        int rw = (ww < HH_ - WS_) ? 0 : ((ww < HH_ - SHIFT_) ? 1 : 2);
        regid[tid] = rh * 3 + rw;
    }
    __syncthreads();

    int n = tid >> 2, qq = tid & 3;
    float qr[32];
#pragma unroll
    for (int e = 0; e < 8; ++e) {
        floatx4 t4 = *(const floatx4*)&qs[n][e * 4];
        qr[e * 4 + 0] = t4[0]; qr[e * 4 + 1] = t4[1];
        qr[e * 4 + 2] = t4[2]; qr[e * 4 + 3] = t4[3];
    }
    int i1 = n >> 3, j1 = n & 7;
    int rg1 = regid[n];
#pragma unroll 4
    for (int mi = 0; mi < 16; ++mi) {
        int m = mi * 4 + qq;
        float d = 0.0f;
#pragma unroll
        for (int e = 0; e < 8; ++e) {
            floatx4 k4 = *(const floatx4*)&ks[m][e * 4];
            d += qr[e * 4 + 0] * k4[0] + qr[e * 4 + 1] * k4[1] +
                 qr[e * 4 + 2] * k4[2] + qr[e * 4 + 3] * k4[3];
        }
        int i2 = m >> 3, j2 = m & 7;
        int rel = (i1 - i2 + 7) * 15 + (j1 - j2 + 7);
        d += rpb[rel * HEADS_ + head];
        if (regid[m] != rg1) d -= 100.0f;
        S[n][m] = d;
    }
    __syncthreads();

    if (tid < 64) {
        float mx = -1e30f;
        for (int m = 0; m < 64; ++m) mx = fmaxf(mx, S[tid][m]);
        float sum = 0.0f;
        for (int m = 0; m < 64; ++m) {
            float e = __expf(S[tid][m] - mx);
            S[tid][m] = e;
            sum += e;
        }
        float rs = 1.0f / sum;
        for (int m = 0; m < 64; ++m) S[tid][m] *= rs;
    }
    __syncthreads();

    int d0 = (tid & 3) * 8;
    float o[8];
#pragma unroll
    for (int e = 0; e < 8; ++e) o[e] = 0.0f;
    for (int m = 0; m < 64; ++m) {
        float p = S[n][m];
        floatx4 va = *(const floatx4*)&vs[m][d0];
        floatx4 vb = *(const floatx4*)&vs[m][d0 + 4];
        o[0] += p * va[0]; o[1] += p * va[1]; o[2] += p * va[2]; o[3] += p * va[3];
        o[4] += p * vb[0]; o[5] += p * vb[1]; o[6] += p * vb[2]; o[7] += p * vb[3];
    }
    ushort8 pk;
#pragma unroll
    for (int e = 0; e < 8; ++e) pk[e] = f2b(o[e]);
    *(ushort8*)(aout + (size_t)(winl * 64 + n) * DIM_ + head * HD_ + d0) = pk;
}

extern "C" void kernel_launch(void* const* d_in, const int* in_sizes, int n_in,
                              void* d_out, int out_size, void* d_ws, size_t ws_size,
                              hipStream_t stream) {
    const float* x      = (const float*)d_in[0];
    const float* ln1_w  = (const float*)d_in[1];
    const float* ln1_b  = (const float*)d_in[2];
    const float* qkv_w  = (const float*)d_in[3];
    const float* qkv_b  = (const float*)d_in[4];
    const float* proj_w = (const float*)d_in[5];
    const float* proj_b = (const float*)d_in[6];
    const float* rpb    = (const float*)d_in[7];
    const float* ln2_w  = (const float*)d_in[8];
    const float* ln2_b  = (const float*)d_in[9];
    const float* fc1_w  = (const float*)d_in[10];
    const float* fc1_b  = (const float*)d_in[11];
    const float* fc2_w  = (const float*)d_in[12];
    const float* fc2_b  = (const float*)d_in[13];

    char* ws = (char*)d_ws;
    size_t off = 0;
    auto alloc = [&](size_t bytes) -> void* {
        void* p = ws + off;
        off += (bytes + 255) & ~(size_t)255;
        return p;
    };
    ushort_t* qkv_wt  = (ushort_t*)alloc((size_t)576 * 192 * 2);
    ushort_t* proj_wt = (ushort_t*)alloc((size_t)192 * 192 * 2);
    ushort_t* fc1_wt  = (ushort_t*)alloc((size_t)768 * 192 * 2);
    ushort_t* fc2_wt  = (ushort_t*)alloc((size_t)192 * 768 * 2);

    // x1 lives in d_out (f32; fully written by proj scatter before any read).
    float* x1 = (float*)d_out;

    // chunkRows multiple of 128 so GEMM 128-row tiles fit exactly.
    size_t budget = (ws_size > off + 4096) ? (ws_size - off - 4096) : 0;
    long rows = (long)(budget / 1920);
    rows = (rows / 128) * 128;
    if (rows < 128) rows = 128;
    if (rows > NTOK_) rows = NTOK_;
    int chunkRows = (int)rows;
    int Wc = chunkRows / 64;            // even
    if (Wc > NWTOT_) Wc = NWTOT_;

    ushort_t* bufS = (ushort_t*)alloc((size_t)chunkRows * 192 * 2);  // xw / attn_out / xn2
    ushort_t* bufL = (ushort_t*)alloc((size_t)chunkRows * 768 * 2);  // qkv / h
    (void)n_in; (void)in_sizes; (void)out_size;

    transpose_kernel<<<(192 * 576 + 255) / 256, 256, 0, stream>>>(qkv_w, qkv_wt, 192, 576);
    transpose_kernel<<<(192 * 192 + 255) / 256, 256, 0, stream>>>(proj_w, proj_wt, 192, 192);
    transpose_kernel<<<(192 * 768 + 255) / 256, 256, 0, stream>>>(fc1_w, fc1_wt, 192, 768);
    transpose_kernel<<<(768 * 192 + 255) / 256, 256, 0, stream>>>(fc2_w, fc2_wt, 768, 192);

    // ---- Phase A: LN1+roll+partition -> qkv -> attention -> proj(+x) -> x1
    for (int w0 = 0; w0 < NWTOT_; w0 += Wc) {
        int wc = NWTOT_ - w0 < Wc ? NWTOT_ - w0 : Wc;
        int rowsA = wc * 64;            // multiple of 128
        ln_kernel<true><<<rowsA / 4, 256, 0, stream>>>(x, ln1_w, ln1_b, bufS, w0 * 64);
        dim3 gq(rowsA / 128, 576 / 192);
        gemm_kernel<EPI_STORE><<<gq, 256, 0, stream>>>(bufS, qkv_wt, qkv_b, bufL, nullptr, 192, 576, 0);
        attn_kernel<<<wc * HEADS_, 256, 0, stream>>>(bufL, rpb, bufS, w0);
        dim3 gp(rowsA / 128, 1);
        gemm_kernel<EPI_PROJ><<<gp, 256, 0, stream>>>(bufS, proj_wt, proj_b, x1, x, 192, 192, w0 * 64);
    }

    // ---- Phase B: LN2 -> fc1+gelu -> fc2(+x1) -> d_out
    for (int t0 = 0; t0 < NTOK_; t0 += chunkRows) {
        int tc = NTOK_ - t0 < chunkRows ? NTOK_ - t0 : chunkRows;
        ln_kernel<false><<<tc / 4, 256, 0, stream>>>(x1 + (size_t)t0 * 192, ln2_w, ln2_b, bufS, 0);
        dim3 g1(tc / 128, 768 / 192);
        gemm_kernel<EPI_GELU><<<g1, 256, 0, stream>>>(bufS, fc1_wt, fc1_b, bufL, nullptr, 192, 768, 0);
        dim3 g2(tc / 128, 1);
        gemm_kernel<EPI_FC2><<<g2, 256, 0, stream>>>(bufL, fc2_wt, fc2_b,
                                                     x1 + (size_t)t0 * 192,
                                                     x1 + (size_t)t0 * 192, 768, 192, 0);
    }
}